// Round 1
// 576.025 us; speedup vs baseline: 2.3197x; 2.3197x over previous
//
#include <hip/hip_runtime.h>

#define Bn 4
#define Nn 40
#define NCUBE 64000   // 40^3

typedef __attribute__((ext_vector_type(8))) short short8;
typedef __attribute__((ext_vector_type(4))) float f32x4;

// ---------------- workspace layout ----------------
// bytes [0, 2048)          : sums[Bn*128] (f32, softmax denominators)
// bytes [2048, 2048+448KB) : bf16 hi/lo weight fragments (unsigned short), offsets below in shorts
#define OFF_WI1H 0
#define OFF_WI1L 16384
#define OFF_WI2H 32768
#define OFF_WI2L 49152
#define OFF_WEH  65536
#define OFF_WEL  81920
#define OFF_WO1H 98304
#define OFF_WO1L 163840
#define WB_SHORTS 229376
#define WS_NEED (2048 + WB_SHORTS*2)

union S8u { short8 v; unsigned u[4]; };

// split f32 -> packed u32: top16 = bf16(hi, trunc), bottom16 = bf16(f - hi, trunc)
__device__ __forceinline__ unsigned packsplit(float f) {
    unsigned u  = __float_as_uint(f);
    unsigned hi = u & 0xFFFF0000u;
    float rem   = f - __uint_as_float(hi);
    return hi | (__float_as_uint(rem) >> 16);
}
__device__ __forceinline__ float unpackf(unsigned u) {
    return __uint_as_float(u & 0xFFFF0000u) + __uint_as_float(u << 16);
}

// 8 f32 -> hi/lo bf16 fragments (k-order preserved)
__device__ __forceinline__ void split8(const float* f, short8& ah, short8& al) {
    S8u A, L;
    #pragma unroll
    for (int p = 0; p < 4; ++p) {
        unsigned u0 = __float_as_uint(f[2*p]);
        unsigned u1 = __float_as_uint(f[2*p+1]);
        unsigned h0 = u0 & 0xFFFF0000u, h1 = u1 & 0xFFFF0000u;
        A.u[p] = (u0 >> 16) | h1;
        float r0 = f[2*p]   - __uint_as_float(h0);
        float r1 = f[2*p+1] - __uint_as_float(h1);
        L.u[p] = (__float_as_uint(r0) >> 16) | (__float_as_uint(r1) & 0xFFFF0000u);
    }
    ah = A.v; al = L.v;
}

// 8 packed u32 -> hi/lo bf16 fragments
__device__ __forceinline__ void unpack8(uint4 q0, uint4 q1, short8& ah, short8& al) {
    unsigned q[8] = {q0.x,q0.y,q0.z,q0.w,q1.x,q1.y,q1.z,q1.w};
    S8u A, L;
    #pragma unroll
    for (int p = 0; p < 4; ++p) {
        unsigned u0 = q[2*p], u1 = q[2*p+1];
        A.u[p] = (u0 >> 16) | (u1 & 0xFFFF0000u);
        L.u[p] = (u0 & 0xFFFFu) | (u1 << 16);
    }
    ah = A.v; al = L.v;
}

// bf16x3 MFMA. Operands SWAPPED (arg0 = W-frag, arg1 = act-frag) so the C/D
// fragment maps to: out_row(M) = 16*mt + (l&15), out_col(N) = 16*nt + 4*(l>>4) + r.
__device__ __forceinline__ f32x4 mfma3(short8 bh, short8 bl, short8 ah, short8 al, f32x4 c) {
    c = __builtin_amdgcn_mfma_f32_16x16x32_bf16(bh, ah, c, 0, 0, 0);
    c = __builtin_amdgcn_mfma_f32_16x16x32_bf16(bh, al, c, 0, 0, 0);
    c = __builtin_amdgcn_mfma_f32_16x16x32_bf16(bl, ah, c, 0, 0, 0);
    return c;
}

// B-fragment loader: PRE = pre-split fragment-contiguous in ws (16B/lane, coalesced);
// fallback converts from the f32 row-major weight on the fly.
template<bool PRE>
__device__ __forceinline__ void load_bfrag(const unsigned short* Wh, const unsigned short* Wl,
                                           const float* W, int N, int NT, int kt, int nt, int l,
                                           short8& bh, short8& bl) {
    if constexpr (PRE) {
        const int off = ((kt*NT + nt)*64 + l)*8;
        bh = *(const short8*)(Wh + off);
        bl = *(const short8*)(Wl + off);
    } else {
        const int col = 16*nt + (l & 15);
        const int k0  = 32*kt + 8*(l >> 4);
        S8u H, L;
        #pragma unroll
        for (int p = 0; p < 4; ++p) {
            float f0 = W[(k0 + 2*p    )*N + col];
            float f1 = W[(k0 + 2*p + 1)*N + col];
            unsigned u0 = __float_as_uint(f0), u1 = __float_as_uint(f1);
            unsigned h0 = u0 & 0xFFFF0000u,  h1 = u1 & 0xFFFF0000u;
            H.u[p] = (u0 >> 16) | h1;
            float r0 = f0 - __uint_as_float(h0);
            float r1 = f1 - __uint_as_float(h1);
            L.u[p] = (__float_as_uint(r0) >> 16) | (__float_as_uint(r1) & 0xFFFF0000u);
        }
        bh = H.v; bl = L.v;
    }
}

// ---------------------------------------------------------------------------
// One-time weight split into B-fragment layout:
// frag(kt,nt): lane l, j=0..7 holds W[32kt + 8*(l>>4) + j][16nt + (l&15)]
// ---------------------------------------------------------------------------
__global__ __launch_bounds__(256)
void prep_kernel(const float* __restrict__ Wi1, const float* __restrict__ Wi2,
                 const float* __restrict__ We,  const float* __restrict__ Wo1,
                 unsigned short* __restrict__ WB) {
    int id = blockIdx.x*256 + threadIdx.x;
    const float* W; int NT, N; unsigned short *Wh, *Wl; int fid;
    if (id < 2048)       { W = Wi1; NT = 8;  N = 128; Wh = WB+OFF_WI1H; Wl = WB+OFF_WI1L; fid = id; }
    else if (id < 4096)  { W = Wi2; NT = 8;  N = 128; Wh = WB+OFF_WI2H; Wl = WB+OFF_WI2L; fid = id-2048; }
    else if (id < 6144)  { W = We;  NT = 8;  N = 128; Wh = WB+OFF_WEH;  Wl = WB+OFF_WEL;  fid = id-4096; }
    else if (id < 14336) { W = Wo1; NT = 16; N = 256; Wh = WB+OFF_WO1H; Wl = WB+OFF_WO1L; fid = id-6144; }
    else return;
    int frag = fid >> 6, l = fid & 63;
    int nt = frag % NT, kt = frag / NT;
    int col = 16*nt + (l & 15), k0 = 32*kt + 8*(l >> 4);
    #pragma unroll
    for (int j = 0; j < 8; ++j) {
        float f = W[(k0 + j)*N + col];
        unsigned u  = __float_as_uint(f);
        unsigned hi = u & 0xFFFF0000u;
        float rem   = f - __uint_as_float(hi);
        Wh[frag*512 + l*8 + j] = (unsigned short)(u >> 16);
        Wl[frag*512 + l*8 + j] = (unsigned short)(__float_as_uint(rem) >> 16);
    }
}

// ---------------------------------------------------------------------------
// Main kernel. 128-row tile, 256 threads = 4 waves; wave w owns N-columns
// [32w,32w+32) of each 128-wide stage (and [64w,64w+64) of the 256-wide stage 4),
// all 8 row-subtiles. SUMS_MODE: stages 1-2 + masked exp-sum (tile early-exit).
// FULL: stages 1-5 fused; stage 4 split into two K=128 GEMMs (xf half, then
// a*xi half) so one 66KB packed hi/lo LDS buffer suffices -> 2 blocks/CU.
// ---------------------------------------------------------------------------
template<bool PRE, bool SUMS_MODE>
__global__ __launch_bounds__(256, 2)
void hyper_kernel(const float* __restrict__ x, const unsigned char* __restrict__ mask,
                  const float* __restrict__ Wi1, const float* __restrict__ bi1,
                  const float* __restrict__ Wi2, const float* __restrict__ bi2,
                  const float* __restrict__ We,
                  const float* __restrict__ Wo1, const float* __restrict__ bo1,
                  const float* __restrict__ Wo2, const float* __restrict__ bo2,
                  float* __restrict__ sums, const unsigned short* __restrict__ WB,
                  float* __restrict__ out) {
    const int tid = threadIdx.x;
    const int l  = tid & 63;
    const int w  = tid >> 6;
    const int lr = l & 15;   // output row within 16-tile
    const int lg = l >> 4;   // k-group / col-quad group
    const int b  = blockIdx.x / 500;
    const int e0 = (blockIdx.x % 500) * 128;

    __shared__ __align__(16) unsigned cbuf[128][132];  // packed hi|lo activations, +4 pad
    __shared__ float red[4][128];
    __shared__ unsigned char mlds[Nn];
    __shared__ int anyv;

    if (tid < Nn) mlds[tid] = mask[b*Nn + tid];
    if (tid == 0) anyv = 0;
    __syncthreads();

    bool valid[8];
    bool lane_any = false;
    #pragma unroll
    for (int mt = 0; mt < 8; ++mt) {
        int e = e0 + 16*mt + lr;
        int k = e % Nn, ij = e / Nn, j = ij % Nn, i = ij / Nn;
        valid[mt] = (i < j) && (j < k) && mlds[i] && mlds[j] && mlds[k];
        lane_any |= valid[mt];
    }
    if (SUMS_MODE) {
        if (lane_any) anyv = 1;
        __syncthreads();
        if (!anyv) return;   // no valid hyperedge in this tile
    }

    // ---- Stage 1: h1 = relu(x @ Wi1 + bi1) -> cbuf ----
    {
        f32x4 acc1[8][2];
        #pragma unroll
        for (int n = 0; n < 2; ++n) {
            const float4 bv = *(const float4*)(bi1 + 16*(2*w + n) + 4*lg);
            #pragma unroll
            for (int mt = 0; mt < 8; ++mt) {
                acc1[mt][n][0]=bv.x; acc1[mt][n][1]=bv.y; acc1[mt][n][2]=bv.z; acc1[mt][n][3]=bv.w;
            }
        }
        for (int kt = 0; kt < 4; ++kt) {
            short8 bh[2], bl[2];
            #pragma unroll
            for (int n = 0; n < 2; ++n)
                load_bfrag<PRE>(WB+OFF_WI1H, WB+OFF_WI1L, Wi1, 128, 8, kt, 2*w+n, l, bh[n], bl[n]);
            #pragma unroll
            for (int mt = 0; mt < 8; ++mt) {
                const float* xp = x + ((long)(b*NCUBE + e0 + 16*mt + lr))*128 + 32*kt + 8*lg;
                const float4 x0 = *(const float4*)xp;
                const float4 x1 = *(const float4*)(xp + 4);
                float fv[8] = {x0.x,x0.y,x0.z,x0.w,x1.x,x1.y,x1.z,x1.w};
                short8 ah, al; split8(fv, ah, al);
                #pragma unroll
                for (int n = 0; n < 2; ++n) acc1[mt][n] = mfma3(bh[n], bl[n], ah, al, acc1[mt][n]);
            }
        }
        #pragma unroll
        for (int mt = 0; mt < 8; ++mt)
            #pragma unroll
            for (int n = 0; n < 2; ++n) {
                uint4 pk;
                pk.x = packsplit(fmaxf(acc1[mt][n][0], 0.f));
                pk.y = packsplit(fmaxf(acc1[mt][n][1], 0.f));
                pk.z = packsplit(fmaxf(acc1[mt][n][2], 0.f));
                pk.w = packsplit(fmaxf(acc1[mt][n][3], 0.f));
                *(uint4*)&cbuf[16*mt + lr][16*(2*w + n) + 4*lg] = pk;
            }
    }
    __syncthreads();

    // ---- Stage 2: xf = h1 @ Wi2 + bi2 (kept in regs) ----
    f32x4 acc2[8][2];
    {
        #pragma unroll
        for (int n = 0; n < 2; ++n) {
            const float4 bv = *(const float4*)(bi2 + 16*(2*w + n) + 4*lg);
            #pragma unroll
            for (int mt = 0; mt < 8; ++mt) {
                acc2[mt][n][0]=bv.x; acc2[mt][n][1]=bv.y; acc2[mt][n][2]=bv.z; acc2[mt][n][3]=bv.w;
            }
        }
        for (int kt = 0; kt < 4; ++kt) {
            short8 bh[2], bl[2];
            #pragma unroll
            for (int n = 0; n < 2; ++n)
                load_bfrag<PRE>(WB+OFF_WI2H, WB+OFF_WI2L, Wi2, 128, 8, kt, 2*w+n, l, bh[n], bl[n]);
            #pragma unroll
            for (int mt = 0; mt < 8; ++mt) {
                short8 ah, al;
                const uint4 q0 = *(const uint4*)&cbuf[16*mt + lr][32*kt + 8*lg];
                const uint4 q1 = *(const uint4*)&cbuf[16*mt + lr][32*kt + 8*lg + 4];
                unpack8(q0, q1, ah, al);
                #pragma unroll
                for (int n = 0; n < 2; ++n) acc2[mt][n] = mfma3(bh[n], bl[n], ah, al, acc2[mt][n]);
            }
        }
    }

    if (SUMS_MODE) {
        // masked sum of exp(xf) over this tile's rows, per channel
        float s[2][4] = {{0,0,0,0},{0,0,0,0}};
        #pragma unroll
        for (int mt = 0; mt < 8; ++mt)
            if (valid[mt])
                #pragma unroll
                for (int n = 0; n < 2; ++n)
                    #pragma unroll
                    for (int r = 0; r < 4; ++r) s[n][r] += __expf(acc2[mt][n][r]);
        #pragma unroll
        for (int n = 0; n < 2; ++n)
            #pragma unroll
            for (int r = 0; r < 4; ++r) {
                float v = s[n][r];
                v += __shfl_xor(v, 1); v += __shfl_xor(v, 2);
                v += __shfl_xor(v, 4); v += __shfl_xor(v, 8);
                if (lr == 0) atomicAdd(&sums[b*128 + 16*(2*w + n) + 4*lg + r], v);
            }
        return;
    }

    // ---- write xf (packed) into cbuf (after everyone is done reading h1) ----
    __syncthreads();
    #pragma unroll
    for (int mt = 0; mt < 8; ++mt)
        #pragma unroll
        for (int n = 0; n < 2; ++n) {
            uint4 pk;
            pk.x = packsplit(acc2[mt][n][0]);
            pk.y = packsplit(acc2[mt][n][1]);
            pk.z = packsplit(acc2[mt][n][2]);
            pk.w = packsplit(acc2[mt][n][3]);
            *(uint4*)&cbuf[16*mt + lr][16*(2*w + n) + 4*lg] = pk;
        }
    __syncthreads();

    // ---- Stage 4b: acc4 = bo1 + xf @ Wo1[128:256, :]  (xf half of h) ----
    f32x4 acc4[8][4];
    #pragma unroll
    for (int n = 0; n < 4; ++n) {
        const float4 bv = *(const float4*)(bo1 + 16*(4*w + n) + 4*lg);
        #pragma unroll
        for (int mt = 0; mt < 8; ++mt) {
            acc4[mt][n][0]=bv.x; acc4[mt][n][1]=bv.y; acc4[mt][n][2]=bv.z; acc4[mt][n][3]=bv.w;
        }
    }
    for (int kt = 0; kt < 4; ++kt) {
        short8 oh[4], ol[4];
        #pragma unroll
        for (int n = 0; n < 4; ++n)
            load_bfrag<PRE>(WB+OFF_WO1H, WB+OFF_WO1L, Wo1, 256, 16, kt + 4, 4*w+n, l, oh[n], ol[n]);
        #pragma unroll
        for (int mt = 0; mt < 8; ++mt) {
            short8 ah, al;
            const uint4 q0 = *(const uint4*)&cbuf[16*mt + lr][32*kt + 8*lg];
            const uint4 q1 = *(const uint4*)&cbuf[16*mt + lr][32*kt + 8*lg + 4];
            unpack8(q0, q1, ah, al);
            #pragma unroll
            for (int n = 0; n < 4; ++n) acc4[mt][n] = mfma3(oh[n], ol[n], ah, al, acc4[mt][n]);
        }
    }

    // ---- Stage 3: xi = relu(xf @ We); then acc3 <- a * xi ----
    f32x4 acc3[8][2];
    #pragma unroll
    for (int mt = 0; mt < 8; ++mt)
        #pragma unroll
        for (int n = 0; n < 2; ++n) { acc3[mt][n][0]=0; acc3[mt][n][1]=0; acc3[mt][n][2]=0; acc3[mt][n][3]=0; }
    for (int kt = 0; kt < 4; ++kt) {
        short8 eh[2], el[2];
        #pragma unroll
        for (int n = 0; n < 2; ++n)
            load_bfrag<PRE>(WB+OFF_WEH, WB+OFF_WEL, We, 128, 8, kt, 2*w+n, l, eh[n], el[n]);
        #pragma unroll
        for (int mt = 0; mt < 8; ++mt) {
            short8 ah, al;
            const uint4 q0 = *(const uint4*)&cbuf[16*mt + lr][32*kt + 8*lg];
            const uint4 q1 = *(const uint4*)&cbuf[16*mt + lr][32*kt + 8*lg + 4];
            unpack8(q0, q1, ah, al);
            #pragma unroll
            for (int n = 0; n < 2; ++n) acc3[mt][n] = mfma3(eh[n], el[n], ah, al, acc3[mt][n]);
        }
    }
    {
        float rinv[2][4];
        #pragma unroll
        for (int n = 0; n < 2; ++n) {
            const float4 sv = *(const float4*)(sums + b*128 + 16*(2*w + n) + 4*lg);
            rinv[n][0] = 1.0f/sv.x; rinv[n][1] = 1.0f/sv.y; rinv[n][2] = 1.0f/sv.z; rinv[n][3] = 1.0f/sv.w;
        }
        #pragma unroll
        for (int mt = 0; mt < 8; ++mt)
            #pragma unroll
            for (int n = 0; n < 2; ++n) {
                const uint4 q = *(const uint4*)&cbuf[16*mt + lr][16*(2*w + n) + 4*lg];
                const unsigned qq[4] = {q.x, q.y, q.z, q.w};
                #pragma unroll
                for (int r = 0; r < 4; ++r) {
                    float aa = valid[mt] ? __expf(unpackf(qq[r])) * rinv[n][r] : 0.0f;
                    acc3[mt][n][r] = aa * fmaxf(acc3[mt][n][r], 0.0f);
                }
            }
    }
    __syncthreads();   // all waves done reading xf
    #pragma unroll
    for (int mt = 0; mt < 8; ++mt)
        #pragma unroll
        for (int n = 0; n < 2; ++n) {
            uint4 pk;
            pk.x = packsplit(acc3[mt][n][0]);
            pk.y = packsplit(acc3[mt][n][1]);
            pk.z = packsplit(acc3[mt][n][2]);
            pk.w = packsplit(acc3[mt][n][3]);
            *(uint4*)&cbuf[16*mt + lr][16*(2*w + n) + 4*lg] = pk;
        }
    __syncthreads();

    // ---- Stage 4a: acc4 += (a*xi) @ Wo1[0:128, :] ----
    for (int kt = 0; kt < 4; ++kt) {
        short8 oh[4], ol[4];
        #pragma unroll
        for (int n = 0; n < 4; ++n)
            load_bfrag<PRE>(WB+OFF_WO1H, WB+OFF_WO1L, Wo1, 256, 16, kt, 4*w+n, l, oh[n], ol[n]);
        #pragma unroll
        for (int mt = 0; mt < 8; ++mt) {
            short8 ah, al;
            const uint4 q0 = *(const uint4*)&cbuf[16*mt + lr][32*kt + 8*lg];
            const uint4 q1 = *(const uint4*)&cbuf[16*mt + lr][32*kt + 8*lg + 4];
            unpack8(q0, q1, ah, al);
            #pragma unroll
            for (int n = 0; n < 4; ++n) acc4[mt][n] = mfma3(oh[n], ol[n], ah, al, acc4[mt][n]);
        }
    }

    // ---- Stage 5: out = relu(g) @ Wo2 + bo2 ----
    {
        float outp[8];
        #pragma unroll
        for (int mt = 0; mt < 8; ++mt) outp[mt] = 0.0f;
        #pragma unroll
        for (int n = 0; n < 4; ++n) {
            const float4 wv = *(const float4*)(Wo2 + 16*(4*w + n) + 4*lg);
            #pragma unroll
            for (int mt = 0; mt < 8; ++mt) {
                outp[mt] += fmaxf(acc4[mt][n][0], 0.f)*wv.x + fmaxf(acc4[mt][n][1], 0.f)*wv.y
                          + fmaxf(acc4[mt][n][2], 0.f)*wv.z + fmaxf(acc4[mt][n][3], 0.f)*wv.w;
            }
        }
        #pragma unroll
        for (int mt = 0; mt < 8; ++mt) {
            outp[mt] += __shfl_xor(outp[mt], 16);
            outp[mt] += __shfl_xor(outp[mt], 32);
        }
        if (lg == 0) {
            #pragma unroll
            for (int mt = 0; mt < 8; ++mt) red[w][16*mt + lr] = outp[mt];
        }
        __syncthreads();
        if (tid < 128)
            out[(long)b*NCUBE + e0 + tid] =
                red[0][tid] + red[1][tid] + red[2][tid] + red[3][tid] + bo2[0];
    }
}

extern "C" void kernel_launch(void* const* d_in, const int* in_sizes, int n_in,
                              void* d_out, int out_size, void* d_ws, size_t ws_size,
                              hipStream_t stream) {
    const float*         x    = (const float*)d_in[0];
    const unsigned char* mask = (const unsigned char*)d_in[1];
    const float* Wi1 = (const float*)d_in[2];
    const float* bi1 = (const float*)d_in[3];
    const float* Wi2 = (const float*)d_in[4];
    const float* bi2 = (const float*)d_in[5];
    const float* We  = (const float*)d_in[6];
    const float* Wo1 = (const float*)d_in[7];
    const float* bo1 = (const float*)d_in[8];
    const float* Wo2 = (const float*)d_in[9];
    const float* bo2 = (const float*)d_in[10];
    float* out  = (float*)d_out;
    float* sums = (float*)d_ws;
    unsigned short* WB = (unsigned short*)((char*)d_ws + 2048);

    hipMemsetAsync(d_ws, 0, Bn*128*sizeof(float), stream);
    if (ws_size >= (size_t)WS_NEED) {
        prep_kernel<<<56, 256, 0, stream>>>(Wi1, Wi2, We, Wo1, WB);
        hyper_kernel<true,  true ><<<Bn*500, 256, 0, stream>>>(x, mask, Wi1, bi1, Wi2, bi2, We,
                                                               Wo1, bo1, Wo2, bo2, sums, WB, out);
        hyper_kernel<true,  false><<<Bn*500, 256, 0, stream>>>(x, mask, Wi1, bi1, Wi2, bi2, We,
                                                               Wo1, bo1, Wo2, bo2, sums, WB, out);
    } else {
        hyper_kernel<false, true ><<<Bn*500, 256, 0, stream>>>(x, mask, Wi1, bi1, Wi2, bi2, We,
                                                               Wo1, bo1, Wo2, bo2, sums, nullptr, out);
        hyper_kernel<false, false><<<Bn*500, 256, 0, stream>>>(x, mask, Wi1, bi1, Wi2, bi2, We,
                                                               Wo1, bo1, Wo2, bo2, sums, nullptr, out);
    }
}

// Round 2
// 398.976 us; speedup vs baseline: 3.3491x; 1.4438x over previous
//
#include <hip/hip_runtime.h>

#define Bn 4
#define Nn 40
#define NCUBE 64000   // 40^3
#define ROWS 64       // rows per block tile
#define BPB (NCUBE/ROWS)   // 1000 blocks per batch

typedef __attribute__((ext_vector_type(8))) short short8;
typedef __attribute__((ext_vector_type(4))) float f32x4;
typedef __attribute__((ext_vector_type(4))) unsigned short us4;

// ---------------- workspace layout ----------------
// bytes [0, 2048)          : sums[Bn*128] (f32 softmax denominators)
// bytes [2048, ...)        : bf16 hi/lo weight fragments (unsigned short), offsets in shorts
#define OFF_WI1H 0
#define OFF_WI1L 16384
#define OFF_WI2H 32768
#define OFF_WI2L 49152
#define OFF_WEH  65536
#define OFF_WEL  81920
#define OFF_WO1H 98304
#define OFF_WO1L 163840
#define WB_SHORTS 229376
#define WS_NEED (2048 + WB_SHORTS*2)

union S8u { short8 v; unsigned u[4]; };

// 8 f32 -> hi/lo bf16 fragments (k-order preserved)
__device__ __forceinline__ void split8(const float* f, short8& ah, short8& al) {
    S8u A, L;
    #pragma unroll
    for (int p = 0; p < 4; ++p) {
        unsigned u0 = __float_as_uint(f[2*p]);
        unsigned u1 = __float_as_uint(f[2*p+1]);
        unsigned h0 = u0 & 0xFFFF0000u, h1 = u1 & 0xFFFF0000u;
        A.u[p] = (u0 >> 16) | h1;
        float r0 = f[2*p]   - __uint_as_float(h0);
        float r1 = f[2*p+1] - __uint_as_float(h1);
        L.u[p] = (__float_as_uint(r0) >> 16) | (__float_as_uint(r1) & 0xFFFF0000u);
    }
    ah = A.v; al = L.v;
}

// f32x4 -> hi/lo bf16 quads
__device__ __forceinline__ void split4(const f32x4 v, us4& h, us4& lo) {
    #pragma unroll
    for (int r = 0; r < 4; ++r) {
        float f = v[r];
        unsigned u  = __float_as_uint(f);
        unsigned hi = u & 0xFFFF0000u;
        float rem   = f - __uint_as_float(hi);
        h[r]  = (unsigned short)(u >> 16);
        lo[r] = (unsigned short)(__float_as_uint(rem) >> 16);
    }
}

// bf16x3 MFMA. Operands SWAPPED (arg0 = W-frag, arg1 = act-frag) so C/D maps to
// out_row(M) = 16*mt + (l&15), out_col(N) = 16*nt + 4*(l>>4) + r.  (verified R1)
__device__ __forceinline__ f32x4 mfma3(short8 bh, short8 bl, short8 ah, short8 al, f32x4 c) {
    c = __builtin_amdgcn_mfma_f32_16x16x32_bf16(bh, ah, c, 0, 0, 0);
    c = __builtin_amdgcn_mfma_f32_16x16x32_bf16(bh, al, c, 0, 0, 0);
    c = __builtin_amdgcn_mfma_f32_16x16x32_bf16(bl, ah, c, 0, 0, 0);
    return c;
}

// B-fragment loader: PRE = pre-split fragment-contiguous in ws (16B/lane, coalesced);
// fallback converts from the f32 row-major weight on the fly.
template<bool PRE>
__device__ __forceinline__ void load_bfrag(const unsigned short* Wh, const unsigned short* Wl,
                                           const float* W, int N, int NT, int kt, int nt, int l,
                                           short8& bh, short8& bl) {
    if constexpr (PRE) {
        const int off = ((kt*NT + nt)*64 + l)*8;
        bh = *(const short8*)(Wh + off);
        bl = *(const short8*)(Wl + off);
    } else {
        const int col = 16*nt + (l & 15);
        const int k0  = 32*kt + 8*(l >> 4);
        S8u H, L;
        #pragma unroll
        for (int p = 0; p < 4; ++p) {
            float f0 = W[(k0 + 2*p    )*N + col];
            float f1 = W[(k0 + 2*p + 1)*N + col];
            unsigned u0 = __float_as_uint(f0), u1 = __float_as_uint(f1);
            unsigned h0 = u0 & 0xFFFF0000u,  h1 = u1 & 0xFFFF0000u;
            H.u[p] = (u0 >> 16) | h1;
            float r0 = f0 - __uint_as_float(h0);
            float r1 = f1 - __uint_as_float(h1);
            L.u[p] = (__float_as_uint(r0) >> 16) | (__float_as_uint(r1) & 0xFFFF0000u);
        }
        bh = H.v; bl = L.v;
    }
}

// ---------------------------------------------------------------------------
// One-time weight split into B-fragment layout:
// frag(kt,nt): lane l, j=0..7 holds W[32kt + 8*(l>>4) + j][16nt + (l&15)]
// ---------------------------------------------------------------------------
__global__ __launch_bounds__(256)
void prep_kernel(const float* __restrict__ Wi1, const float* __restrict__ Wi2,
                 const float* __restrict__ We,  const float* __restrict__ Wo1,
                 unsigned short* __restrict__ WB) {
    int id = blockIdx.x*256 + threadIdx.x;
    const float* W; int NT, N; unsigned short *Wh, *Wl; int fid;
    if (id < 2048)       { W = Wi1; NT = 8;  N = 128; Wh = WB+OFF_WI1H; Wl = WB+OFF_WI1L; fid = id; }
    else if (id < 4096)  { W = Wi2; NT = 8;  N = 128; Wh = WB+OFF_WI2H; Wl = WB+OFF_WI2L; fid = id-2048; }
    else if (id < 6144)  { W = We;  NT = 8;  N = 128; Wh = WB+OFF_WEH;  Wl = WB+OFF_WEL;  fid = id-4096; }
    else if (id < 14336) { W = Wo1; NT = 16; N = 256; Wh = WB+OFF_WO1H; Wl = WB+OFF_WO1L; fid = id-6144; }
    else return;
    int frag = fid >> 6, l = fid & 63;
    int nt = frag % NT, kt = frag / NT;
    int col = 16*nt + (l & 15), k0 = 32*kt + 8*(l >> 4);
    #pragma unroll
    for (int j = 0; j < 8; ++j) {
        float f = W[(k0 + j)*N + col];
        unsigned u  = __float_as_uint(f);
        unsigned hi = u & 0xFFFF0000u;
        float rem   = f - __uint_as_float(hi);
        Wh[frag*512 + l*8 + j] = (unsigned short)(u >> 16);
        Wl[frag*512 + l*8 + j] = (unsigned short)(__float_as_uint(rem) >> 16);
    }
}

// ---------------------------------------------------------------------------
// Main kernel. 64-row tile, 256 threads = 4 waves; wave w owns N-cols
// [32w,32w+32) of 128-wide stages and [64w,64w+64) of the 256-wide stage 4.
// Activations live in LDS as SEPARATE hi/lo bf16 arrays so MFMA A-fragments
// come straight from ds_read_b128 (no unpack VALU).
// LDS column map: [0,128) = h1, later overwritten by a*xi; [128,256) = xf.
// Stage 4 is one K=256 pass over h = [a*xi, xf].
// Accumulators per wave: max live = acc4[4][4] (64 VGPR) -> no spill.
// ---------------------------------------------------------------------------
template<bool PRE, bool SUMS_MODE>
__global__ __launch_bounds__(256, 2)
void hyper_kernel(const float* __restrict__ x, const unsigned char* __restrict__ mask,
                  const float* __restrict__ Wi1, const float* __restrict__ bi1,
                  const float* __restrict__ Wi2, const float* __restrict__ bi2,
                  const float* __restrict__ We,
                  const float* __restrict__ Wo1, const float* __restrict__ bo1,
                  const float* __restrict__ Wo2, const float* __restrict__ bo2,
                  float* __restrict__ sums, const unsigned short* __restrict__ WB,
                  float* __restrict__ out) {
    const int tid = threadIdx.x;
    const int l  = tid & 63;
    const int w  = tid >> 6;
    const int lr = l & 15;   // output row within 16-tile
    const int lg = l >> 4;   // k-group / col-quad group
    const int b  = blockIdx.x / BPB;
    const int e0 = (blockIdx.x % BPB) * ROWS;

    __shared__ __align__(16) unsigned short hbH[ROWS][264];  // bf16 hi, +8 pad
    __shared__ __align__(16) unsigned short hbL[ROWS][264];  // bf16 lo
    __shared__ float red[4][ROWS];
    __shared__ unsigned char mlds[Nn];
    __shared__ int anyv;

    if (tid < Nn) mlds[tid] = mask[b*Nn + tid];
    if (tid == 0) anyv = 0;
    __syncthreads();

    bool valid[4];
    bool lane_any = false;
    #pragma unroll
    for (int mt = 0; mt < 4; ++mt) {
        int e = e0 + 16*mt + lr;
        int k = e % Nn, ij = e / Nn, j = ij % Nn, i = ij / Nn;
        valid[mt] = (i < j) && (j < k) && mlds[i] && mlds[j] && mlds[k];
        lane_any |= valid[mt];
    }
    if (SUMS_MODE) {
        if (lane_any) anyv = 1;
        __syncthreads();
        if (!anyv) return;   // no valid hyperedge in this tile
    }

    // ---- Stage 1: h1 = relu(x @ Wi1 + bi1) -> LDS cols [0,128) ----
    {
        f32x4 acc1[4][2];
        #pragma unroll
        for (int n = 0; n < 2; ++n) {
            const float4 bv = *(const float4*)(bi1 + 16*(2*w + n) + 4*lg);
            #pragma unroll
            for (int mt = 0; mt < 4; ++mt) {
                acc1[mt][n][0]=bv.x; acc1[mt][n][1]=bv.y; acc1[mt][n][2]=bv.z; acc1[mt][n][3]=bv.w;
            }
        }
        for (int kt = 0; kt < 4; ++kt) {
            short8 bh[2], bl[2];
            #pragma unroll
            for (int n = 0; n < 2; ++n)
                load_bfrag<PRE>(WB+OFF_WI1H, WB+OFF_WI1L, Wi1, 128, 8, kt, 2*w+n, l, bh[n], bl[n]);
            #pragma unroll
            for (int mt = 0; mt < 4; ++mt) {
                const float* xp = x + ((long)(b*NCUBE + e0 + 16*mt + lr))*128 + 32*kt + 8*lg;
                const float4 x0 = *(const float4*)xp;
                const float4 x1 = *(const float4*)(xp + 4);
                float fv[8] = {x0.x,x0.y,x0.z,x0.w,x1.x,x1.y,x1.z,x1.w};
                short8 ah, al; split8(fv, ah, al);
                #pragma unroll
                for (int n = 0; n < 2; ++n) acc1[mt][n] = mfma3(bh[n], bl[n], ah, al, acc1[mt][n]);
            }
        }
        #pragma unroll
        for (int mt = 0; mt < 4; ++mt)
            #pragma unroll
            for (int n = 0; n < 2; ++n) {
                f32x4 v;
                v[0]=fmaxf(acc1[mt][n][0],0.f); v[1]=fmaxf(acc1[mt][n][1],0.f);
                v[2]=fmaxf(acc1[mt][n][2],0.f); v[3]=fmaxf(acc1[mt][n][3],0.f);
                us4 h, lo; split4(v, h, lo);
                *(us4*)&hbH[16*mt + lr][16*(2*w + n) + 4*lg] = h;
                *(us4*)&hbL[16*mt + lr][16*(2*w + n) + 4*lg] = lo;
            }
    }
    __syncthreads();

    // ---- Stage 2: xf = h1 @ Wi2 + bi2 (kept in regs as acc2) ----
    f32x4 acc2[4][2];
    {
        #pragma unroll
        for (int n = 0; n < 2; ++n) {
            const float4 bv = *(const float4*)(bi2 + 16*(2*w + n) + 4*lg);
            #pragma unroll
            for (int mt = 0; mt < 4; ++mt) {
                acc2[mt][n][0]=bv.x; acc2[mt][n][1]=bv.y; acc2[mt][n][2]=bv.z; acc2[mt][n][3]=bv.w;
            }
        }
        for (int kt = 0; kt < 4; ++kt) {
            short8 bh[2], bl[2];
            #pragma unroll
            for (int n = 0; n < 2; ++n)
                load_bfrag<PRE>(WB+OFF_WI2H, WB+OFF_WI2L, Wi2, 128, 8, kt, 2*w+n, l, bh[n], bl[n]);
            #pragma unroll
            for (int mt = 0; mt < 4; ++mt) {
                const short8 ah = *(const short8*)&hbH[16*mt + lr][32*kt + 8*lg];
                const short8 al = *(const short8*)&hbL[16*mt + lr][32*kt + 8*lg];
                #pragma unroll
                for (int n = 0; n < 2; ++n) acc2[mt][n] = mfma3(bh[n], bl[n], ah, al, acc2[mt][n]);
            }
        }
    }

    if (SUMS_MODE) {
        // masked sum of exp(xf) over this tile's rows, per channel
        float s[2][4] = {{0,0,0,0},{0,0,0,0}};
        #pragma unroll
        for (int mt = 0; mt < 4; ++mt)
            if (valid[mt])
                #pragma unroll
                for (int n = 0; n < 2; ++n)
                    #pragma unroll
                    for (int r = 0; r < 4; ++r) s[n][r] += __expf(acc2[mt][n][r]);
        #pragma unroll
        for (int n = 0; n < 2; ++n)
            #pragma unroll
            for (int r = 0; r < 4; ++r) {
                float v = s[n][r];
                v += __shfl_xor(v, 1); v += __shfl_xor(v, 2);
                v += __shfl_xor(v, 4); v += __shfl_xor(v, 8);
                if (lr == 0) atomicAdd(&sums[b*128 + 16*(2*w + n) + 4*lg + r], v);
            }
        return;
    }

    // ---- write xf -> LDS cols [128,256) ----
    #pragma unroll
    for (int mt = 0; mt < 4; ++mt)
        #pragma unroll
        for (int n = 0; n < 2; ++n) {
            us4 h, lo; split4(acc2[mt][n], h, lo);
            *(us4*)&hbH[16*mt + lr][128 + 16*(2*w + n) + 4*lg] = h;
            *(us4*)&hbL[16*mt + lr][128 + 16*(2*w + n) + 4*lg] = lo;
        }
    __syncthreads();

    // ---- Stage 3: xi = relu(xf @ We); acc3 <- a * xi; write -> cols [0,128) ----
    {
        f32x4 acc3[4][2];
        #pragma unroll
        for (int mt = 0; mt < 4; ++mt)
            #pragma unroll
            for (int n = 0; n < 2; ++n) { acc3[mt][n][0]=0; acc3[mt][n][1]=0; acc3[mt][n][2]=0; acc3[mt][n][3]=0; }
        for (int kt = 0; kt < 4; ++kt) {
            short8 eh[2], el[2];
            #pragma unroll
            for (int n = 0; n < 2; ++n)
                load_bfrag<PRE>(WB+OFF_WEH, WB+OFF_WEL, We, 128, 8, kt, 2*w+n, l, eh[n], el[n]);
            #pragma unroll
            for (int mt = 0; mt < 4; ++mt) {
                const short8 ah = *(const short8*)&hbH[16*mt + lr][128 + 32*kt + 8*lg];
                const short8 al = *(const short8*)&hbL[16*mt + lr][128 + 32*kt + 8*lg];
                #pragma unroll
                for (int n = 0; n < 2; ++n) acc3[mt][n] = mfma3(eh[n], el[n], ah, al, acc3[mt][n]);
            }
        }
        float rinv[2][4];
        #pragma unroll
        for (int n = 0; n < 2; ++n) {
            const float4 sv = *(const float4*)(sums + b*128 + 16*(2*w + n) + 4*lg);
            rinv[n][0] = 1.0f/sv.x; rinv[n][1] = 1.0f/sv.y; rinv[n][2] = 1.0f/sv.z; rinv[n][3] = 1.0f/sv.w;
        }
        // writes to cols [0,128) are safe: after sync2 nobody reads h1; s3 reads only [128,256)
        #pragma unroll
        for (int mt = 0; mt < 4; ++mt)
            #pragma unroll
            for (int n = 0; n < 2; ++n) {
                f32x4 v;
                #pragma unroll
                for (int r = 0; r < 4; ++r) {
                    const float aa = valid[mt] ? __expf(acc2[mt][n][r]) * rinv[n][r] : 0.0f;
                    v[r] = aa * fmaxf(acc3[mt][n][r], 0.0f);
                }
                us4 h, lo; split4(v, h, lo);
                *(us4*)&hbH[16*mt + lr][16*(2*w + n) + 4*lg] = h;
                *(us4*)&hbL[16*mt + lr][16*(2*w + n) + 4*lg] = lo;
            }
    }
    __syncthreads();

    // ---- Stage 4: g = relu(h @ Wo1 + bo1), single K=256 pass over h=[a*xi, xf] ----
    f32x4 acc4[4][4];
    #pragma unroll
    for (int n = 0; n < 4; ++n) {
        const float4 bv = *(const float4*)(bo1 + 16*(4*w + n) + 4*lg);
        #pragma unroll
        for (int mt = 0; mt < 4; ++mt) {
            acc4[mt][n][0]=bv.x; acc4[mt][n][1]=bv.y; acc4[mt][n][2]=bv.z; acc4[mt][n][3]=bv.w;
        }
    }
    for (int kt = 0; kt < 8; ++kt) {
        short8 oh[4], ol[4];
        #pragma unroll
        for (int n = 0; n < 4; ++n)
            load_bfrag<PRE>(WB+OFF_WO1H, WB+OFF_WO1L, Wo1, 256, 16, kt, 4*w+n, l, oh[n], ol[n]);
        #pragma unroll
        for (int mt = 0; mt < 4; ++mt) {
            const short8 ah = *(const short8*)&hbH[16*mt + lr][32*kt + 8*lg];
            const short8 al = *(const short8*)&hbL[16*mt + lr][32*kt + 8*lg];
            #pragma unroll
            for (int n = 0; n < 4; ++n) acc4[mt][n] = mfma3(oh[n], ol[n], ah, al, acc4[mt][n]);
        }
    }

    // ---- Stage 5: out = relu(g) @ Wo2 + bo2, reduce 256 -> 1 per row ----
    {
        float outp[4];
        #pragma unroll
        for (int mt = 0; mt < 4; ++mt) outp[mt] = 0.0f;
        #pragma unroll
        for (int n = 0; n < 4; ++n) {
            const float4 wv = *(const float4*)(Wo2 + 16*(4*w + n) + 4*lg);
            #pragma unroll
            for (int mt = 0; mt < 4; ++mt) {
                outp[mt] += fmaxf(acc4[mt][n][0], 0.f)*wv.x + fmaxf(acc4[mt][n][1], 0.f)*wv.y
                          + fmaxf(acc4[mt][n][2], 0.f)*wv.z + fmaxf(acc4[mt][n][3], 0.f)*wv.w;
            }
        }
        #pragma unroll
        for (int mt = 0; mt < 4; ++mt) {
            outp[mt] += __shfl_xor(outp[mt], 16);
            outp[mt] += __shfl_xor(outp[mt], 32);
        }
        if (lg == 0) {
            #pragma unroll
            for (int mt = 0; mt < 4; ++mt) red[w][16*mt + lr] = outp[mt];
        }
        __syncthreads();
        if (tid < ROWS)
            out[(long)b*NCUBE + e0 + tid] =
                red[0][tid] + red[1][tid] + red[2][tid] + red[3][tid] + bo2[0];
    }
}

extern "C" void kernel_launch(void* const* d_in, const int* in_sizes, int n_in,
                              void* d_out, int out_size, void* d_ws, size_t ws_size,
                              hipStream_t stream) {
    const float*         x    = (const float*)d_in[0];
    const unsigned char* mask = (const unsigned char*)d_in[1];
    const float* Wi1 = (const float*)d_in[2];
    const float* bi1 = (const float*)d_in[3];
    const float* Wi2 = (const float*)d_in[4];
    const float* bi2 = (const float*)d_in[5];
    const float* We  = (const float*)d_in[6];
    const float* Wo1 = (const float*)d_in[7];
    const float* bo1 = (const float*)d_in[8];
    const float* Wo2 = (const float*)d_in[9];
    const float* bo2 = (const float*)d_in[10];
    float* out  = (float*)d_out;
    float* sums = (float*)d_ws;
    unsigned short* WB = (unsigned short*)((char*)d_ws + 2048);

    hipMemsetAsync(d_ws, 0, Bn*128*sizeof(float), stream);
    if (ws_size >= (size_t)WS_NEED) {
        prep_kernel<<<56, 256, 0, stream>>>(Wi1, Wi2, We, Wo1, WB);
        hyper_kernel<true,  true ><<<Bn*BPB, 256, 0, stream>>>(x, mask, Wi1, bi1, Wi2, bi2, We,
                                                               Wo1, bo1, Wo2, bo2, sums, WB, out);
        hyper_kernel<true,  false><<<Bn*BPB, 256, 0, stream>>>(x, mask, Wi1, bi1, Wi2, bi2, We,
                                                               Wo1, bo1, Wo2, bo2, sums, WB, out);
    } else {
        hyper_kernel<false, true ><<<Bn*BPB, 256, 0, stream>>>(x, mask, Wi1, bi1, Wi2, bi2, We,
                                                               Wo1, bo1, Wo2, bo2, sums, nullptr, out);
        hyper_kernel<false, false><<<Bn*BPB, 256, 0, stream>>>(x, mask, Wi1, bi1, Wi2, bi2, We,
                                                               Wo1, bo1, Wo2, bo2, sums, nullptr, out);
    }
}

// Round 3
// 321.825 us; speedup vs baseline: 4.1520x; 1.2397x over previous
//
#include <hip/hip_runtime.h>

#define Bn 4
#define Nn 40
#define NCUBE 64000   // 40^3
#define ROWS 64       // rows per tile
#define BPB  1000     // full/dense-sums blocks per batch
#define MAXV 16384    // valid-row list capacity per batch (>= C(40,3)=9880)
#define CBLK 160      // compact-sums blocks per batch (160*64 >= 9880)

typedef __attribute__((ext_vector_type(8))) short short8;
typedef __attribute__((ext_vector_type(4))) float f32x4;
typedef __attribute__((ext_vector_type(4))) unsigned short us4;

// ---------------- workspace layout (bytes) ----------------
// 0      : sums[Bn*128] f32
// 2048   : cnt[Bn] int
// 4096   : vlist[Bn*MAXV] int                (compact tier only)
// WBOFF  : bf16 hi/lo weight fragments (ushort)
#define OFF_WI1H 0
#define OFF_WI1L 16384
#define OFF_WI2H 32768
#define OFF_WI2L 49152
#define OFF_WEH  65536
#define OFF_WEL  81920
#define OFF_WO1H 98304
#define OFF_WO1L 163840
#define WB_SHORTS 229376
#define WB_BYTES  (WB_SHORTS*2)
#define WBOFF_COMPACT (4096 + Bn*MAXV*4)
#define WBOFF_SMALL   2560

union S8u { short8 v; unsigned u[4]; };

// XOR-swizzled LDS offset (ushort index) for a [64][256]-ushort tile.
// 16-B granule g is XORed with (row&7): spreads b128 reads across banks
// while keeping 8/16-B alignment and staying inside each 128-B region.
__device__ __forceinline__ int swzofs(int row, int col) {
    int g = col >> 3, sub = col & 7;
    g = (g & ~7) | ((g ^ row) & 7);
    return row*256 + g*8 + sub;
}

// f32x4 -> hi/lo bf16 quads (hi = trunc, lo = bf16(f - hi))
__device__ __forceinline__ void split4(const f32x4 v, us4& h, us4& lo) {
    #pragma unroll
    for (int r = 0; r < 4; ++r) {
        float f = v[r];
        unsigned u  = __float_as_uint(f);
        unsigned hi = u & 0xFFFF0000u;
        float rem   = f - __uint_as_float(hi);
        h[r]  = (unsigned short)(u >> 16);
        lo[r] = (unsigned short)(__float_as_uint(rem) >> 16);
    }
}

// bf16x3 MFMA. Operands SWAPPED (arg0 = W-frag, arg1 = act-frag) so C/D maps to
// out_row(M) = 16*mt + (l&15), out_col(N) = 16*nt + 4*(l>>4) + r.  (verified R1/R2)
__device__ __forceinline__ f32x4 mfma3(short8 bh, short8 bl, short8 ah, short8 al, f32x4 c) {
    c = __builtin_amdgcn_mfma_f32_16x16x32_bf16(bh, ah, c, 0, 0, 0);
    c = __builtin_amdgcn_mfma_f32_16x16x32_bf16(bh, al, c, 0, 0, 0);
    c = __builtin_amdgcn_mfma_f32_16x16x32_bf16(bl, ah, c, 0, 0, 0);
    return c;
}

// B-fragment loader: PRE = pre-split fragment-contiguous in ws; fallback converts
// from the f32 row-major weight on the fly.
template<bool PRE>
__device__ __forceinline__ void load_bfrag(const unsigned short* Wh, const unsigned short* Wl,
                                           const float* W, int N, int NT, int kt, int nt, int l,
                                           short8& bh, short8& bl) {
    if constexpr (PRE) {
        const int off = ((kt*NT + nt)*64 + l)*8;
        bh = *(const short8*)(Wh + off);
        bl = *(const short8*)(Wl + off);
    } else {
        const int col = 16*nt + (l & 15);
        const int k0  = 32*kt + 8*(l >> 4);
        S8u H, L;
        #pragma unroll
        for (int p = 0; p < 4; ++p) {
            float f0 = W[(k0 + 2*p    )*N + col];
            float f1 = W[(k0 + 2*p + 1)*N + col];
            unsigned u0 = __float_as_uint(f0), u1 = __float_as_uint(f1);
            unsigned h0 = u0 & 0xFFFF0000u,  h1 = u1 & 0xFFFF0000u;
            H.u[p] = (u0 >> 16) | h1;
            float r0 = f0 - __uint_as_float(h0);
            float r1 = f1 - __uint_as_float(h1);
            L.u[p] = (__float_as_uint(r0) >> 16) | (__float_as_uint(r1) & 0xFFFF0000u);
        }
        bh = H.v; bl = L.v;
    }
}

// ---------------------------------------------------------------------------
// One-time weight split into B-fragment layout:
// frag(kt,nt): lane l, j=0..7 holds W[32kt + 8*(l>>4) + j][16nt + (l&15)]
// ---------------------------------------------------------------------------
__global__ __launch_bounds__(256)
void prep_kernel(const float* __restrict__ Wi1, const float* __restrict__ Wi2,
                 const float* __restrict__ We,  const float* __restrict__ Wo1,
                 unsigned short* __restrict__ WB) {
    int id = blockIdx.x*256 + threadIdx.x;
    const float* W; int NT, N; unsigned short *Wh, *Wl; int fid;
    if (id < 2048)       { W = Wi1; NT = 8;  N = 128; Wh = WB+OFF_WI1H; Wl = WB+OFF_WI1L; fid = id; }
    else if (id < 4096)  { W = Wi2; NT = 8;  N = 128; Wh = WB+OFF_WI2H; Wl = WB+OFF_WI2L; fid = id-2048; }
    else if (id < 6144)  { W = We;  NT = 8;  N = 128; Wh = WB+OFF_WEH;  Wl = WB+OFF_WEL;  fid = id-4096; }
    else if (id < 14336) { W = Wo1; NT = 16; N = 256; Wh = WB+OFF_WO1H; Wl = WB+OFF_WO1L; fid = id-6144; }
    else return;
    int frag = fid >> 6, l = fid & 63;
    int nt = frag % NT, kt = frag / NT;
    int col = 16*nt + (l & 15), k0 = 32*kt + 8*(l >> 4);
    #pragma unroll
    for (int j = 0; j < 8; ++j) {
        float f = W[(k0 + j)*N + col];
        unsigned u  = __float_as_uint(f);
        unsigned hi = u & 0xFFFF0000u;
        float rem   = f - __uint_as_float(hi);
        Wh[frag*512 + l*8 + j] = (unsigned short)(u >> 16);
        Wl[frag*512 + l*8 + j] = (unsigned short)(__float_as_uint(rem) >> 16);
    }
}

// ---------------------------------------------------------------------------
// Ballot-compaction of valid rows: vlist[b][0..cnt[b]) = e-indices with
// (i<j<k) && mask. Order scrambled (irrelevant: sum is commutative-ish).
// ---------------------------------------------------------------------------
__global__ __launch_bounds__(256)
void count_valid(const unsigned char* __restrict__ mask,
                 int* __restrict__ cnt, int* __restrict__ vlist) {
    const int b = blockIdx.x / 250;
    const int e = (blockIdx.x % 250)*256 + threadIdx.x;
    const int k = e % Nn, ij = e / Nn, j = ij % Nn, i = ij / Nn;
    const bool v = (i < j) && (j < k) && mask[b*Nn+i] && mask[b*Nn+j] && mask[b*Nn+k];
    const unsigned long long m = __ballot(v);
    const int lane = threadIdx.x & 63;
    const int c = __popcll(m);
    int base = 0;
    if (lane == 0 && c) base = atomicAdd(&cnt[b], c);
    base = __shfl(base, 0);
    if (v) vlist[b*MAXV + base + __popcll(m & ((1ull<<lane)-1ull))] = e;
}

// ---------------------------------------------------------------------------
// Sums kernel: stages 1-2 + masked exp-sum. 512 threads = 8 waves, wave w owns
// output cols [16w,16w+16). COMPACT: rows gathered from vlist (all valid).
// DENSE fallback: contiguous tile + any-valid early exit.
// x is cooperatively pre-split into LDS cols [128,256) (phase A).
// ---------------------------------------------------------------------------
template<bool PRE, bool COMPACT>
__global__ __launch_bounds__(512, 4)
void sums_kernel(const float* __restrict__ x, const unsigned char* __restrict__ mask,
                 const float* __restrict__ Wi1, const float* __restrict__ bi1,
                 const float* __restrict__ Wi2, const float* __restrict__ bi2,
                 float* __restrict__ sums, const int* __restrict__ cnt,
                 const int* __restrict__ vlist, const unsigned short* __restrict__ WB)
{
    const int tid = threadIdx.x;
    const int l = tid & 63, w = tid >> 6, lr = l & 15, lg = l >> 4;
    int b, r0;
    if (COMPACT) { b = blockIdx.x / CBLK; r0 = (blockIdx.x % CBLK)*ROWS; if (r0 >= cnt[b]) return; }
    else         { b = blockIdx.x / BPB;  r0 = (blockIdx.x % BPB)*ROWS; }

    __shared__ __align__(16) unsigned short hbH[ROWS*256];
    __shared__ __align__(16) unsigned short hbL[ROWS*256];
    __shared__ int earr[ROWS];
    __shared__ unsigned char mlds[Nn];
    __shared__ int anyv;

    if (!COMPACT) { if (tid < Nn) mlds[tid] = mask[b*Nn + tid]; if (tid == 0) anyv = 0; }
    if (tid < ROWS) {
        if (COMPACT) { int r = r0 + tid; earr[tid] = (r < cnt[b]) ? vlist[b*MAXV + r] : -1; }
        else earr[tid] = r0 + tid;
    }
    __syncthreads();

    bool rv[4];
    if (!COMPACT) {
        bool any = false;
        #pragma unroll
        for (int mt = 0; mt < 4; ++mt) {
            int e = earr[16*mt + lr];
            int k = e % Nn, ij = e / Nn, j = ij % Nn, i = ij / Nn;
            rv[mt] = (i < j) && (j < k) && mlds[i] && mlds[j] && mlds[k];
            any |= rv[mt];
        }
        if (any) anyv = 1;
        __syncthreads();
        if (!anyv) return;
    } else {
        #pragma unroll
        for (int mt = 0; mt < 4; ++mt) rv[mt] = (earr[16*mt + lr] >= 0);
    }

    // phase A: gather x rows, split once, store to LDS cols [128,256)
    #pragma unroll
    for (int p = 0; p < 4; ++p) {
        const int row = p*16 + (tid >> 5);
        const int c0  = (tid & 31)*4;
        int e = earr[row]; if (e < 0) e = 0;
        const float4 xv = *(const float4*)&x[((long)(b*NCUBE + e))*128 + c0];
        f32x4 v; v[0]=xv.x; v[1]=xv.y; v[2]=xv.z; v[3]=xv.w;
        us4 h, lo; split4(v, h, lo);
        const int o = swzofs(row, 128 + c0);
        *(us4*)&hbH[o] = h; *(us4*)&hbL[o] = lo;
    }
    __syncthreads();

    // stage 1: h1 = relu(x @ Wi1 + bi1) -> cols [0,128)
    f32x4 acc[4];
    {
        const float4 bv = *(const float4*)(bi1 + 16*w + 4*lg);
        #pragma unroll
        for (int mt = 0; mt < 4; ++mt) { acc[mt][0]=bv.x; acc[mt][1]=bv.y; acc[mt][2]=bv.z; acc[mt][3]=bv.w; }
        for (int kt = 0; kt < 4; ++kt) {
            short8 bh, bl;
            load_bfrag<PRE>(WB+OFF_WI1H, WB+OFF_WI1L, Wi1, 128, 8, kt, w, l, bh, bl);
            #pragma unroll
            for (int mt = 0; mt < 4; ++mt) {
                const int o = swzofs(16*mt + lr, 128 + 32*kt + 8*lg);
                acc[mt] = mfma3(bh, bl, *(const short8*)&hbH[o], *(const short8*)&hbL[o], acc[mt]);
            }
        }
        #pragma unroll
        for (int mt = 0; mt < 4; ++mt) {
            f32x4 v;
            #pragma unroll
            for (int r = 0; r < 4; ++r) v[r] = fmaxf(acc[mt][r], 0.f);
            us4 h, lo; split4(v, h, lo);
            const int o = swzofs(16*mt + lr, 16*w + 4*lg);
            *(us4*)&hbH[o] = h; *(us4*)&hbL[o] = lo;
        }
    }
    __syncthreads();

    // stage 2: xf = h1 @ Wi2 + bi2
    {
        const float4 bv = *(const float4*)(bi2 + 16*w + 4*lg);
        #pragma unroll
        for (int mt = 0; mt < 4; ++mt) { acc[mt][0]=bv.x; acc[mt][1]=bv.y; acc[mt][2]=bv.z; acc[mt][3]=bv.w; }
        for (int kt = 0; kt < 4; ++kt) {
            short8 bh, bl;
            load_bfrag<PRE>(WB+OFF_WI2H, WB+OFF_WI2L, Wi2, 128, 8, kt, w, l, bh, bl);
            #pragma unroll
            for (int mt = 0; mt < 4; ++mt) {
                const int o = swzofs(16*mt + lr, 32*kt + 8*lg);
                acc[mt] = mfma3(bh, bl, *(const short8*)&hbH[o], *(const short8*)&hbL[o], acc[mt]);
            }
        }
    }

    // masked exp-sum, reduce over rows (lr), one atomic per col
    float s[4] = {0.f, 0.f, 0.f, 0.f};
    #pragma unroll
    for (int mt = 0; mt < 4; ++mt)
        if (rv[mt])
            #pragma unroll
            for (int r = 0; r < 4; ++r) s[r] += __expf(acc[mt][r]);
    #pragma unroll
    for (int r = 0; r < 4; ++r) {
        float v = s[r];
        v += __shfl_xor(v, 1); v += __shfl_xor(v, 2);
        v += __shfl_xor(v, 4); v += __shfl_xor(v, 8);
        if (lr == 0) atomicAdd(&sums[b*128 + 16*w + 4*lg + r], v);
    }
}

// ---------------------------------------------------------------------------
// Full kernel: all 5 stages, all rows. 512 threads = 8 waves; wave w owns cols
// [16w,16w+16) of 128-wide stages and [32w,32w+32) of stage 4 (nt = 2w, 2w+1).
// LDS: one 64x256-bf16 hi/lo tile (XOR-swizzled). Timeline:
//   phA: x -> cols[128,256) | s1: h1 -> [0,128) | s2: xf(regs) -> [128,256)
//   s3: a*xi -> [0,128) | s4: K=256 over h=[a*xi, xf] | s5: 256->1 reduce.
// ---------------------------------------------------------------------------
template<bool PRE>
__global__ __launch_bounds__(512, 4)
void full_kernel(const float* __restrict__ x, const unsigned char* __restrict__ mask,
                 const float* __restrict__ Wi1, const float* __restrict__ bi1,
                 const float* __restrict__ Wi2, const float* __restrict__ bi2,
                 const float* __restrict__ We,
                 const float* __restrict__ Wo1, const float* __restrict__ bo1,
                 const float* __restrict__ Wo2, const float* __restrict__ bo2,
                 const float* __restrict__ sums, const unsigned short* __restrict__ WB,
                 float* __restrict__ out)
{
    const int tid = threadIdx.x;
    const int l = tid & 63, w = tid >> 6, lr = l & 15, lg = l >> 4;
    const int b = blockIdx.x / BPB;
    const int e0 = (blockIdx.x % BPB) * ROWS;

    __shared__ __align__(16) unsigned short hbH[ROWS*256];
    __shared__ __align__(16) unsigned short hbL[ROWS*256];
    __shared__ float red[8][ROWS];
    __shared__ unsigned char mlds[Nn];

    if (tid < Nn) mlds[tid] = mask[b*Nn + tid];

    // phase A: x tile -> LDS cols [128,256), split once per element
    #pragma unroll
    for (int p = 0; p < 4; ++p) {
        const int row = p*16 + (tid >> 5);
        const int c0  = (tid & 31)*4;
        const float4 xv = *(const float4*)&x[((long)(b*NCUBE + e0 + row))*128 + c0];
        f32x4 v; v[0]=xv.x; v[1]=xv.y; v[2]=xv.z; v[3]=xv.w;
        us4 h, lo; split4(v, h, lo);
        const int o = swzofs(row, 128 + c0);
        *(us4*)&hbH[o] = h; *(us4*)&hbL[o] = lo;
    }
    __syncthreads();

    bool valid[4];
    #pragma unroll
    for (int mt = 0; mt < 4; ++mt) {
        int e = e0 + 16*mt + lr;
        int k = e % Nn, ij = e / Nn, j = ij % Nn, i = ij / Nn;
        valid[mt] = (i < j) && (j < k) && mlds[i] && mlds[j] && mlds[k];
    }

    // ---- stage 1: h1 = relu(x @ Wi1 + bi1) -> cols [0,128) ----
    {
        f32x4 acc1[4];
        const float4 bv = *(const float4*)(bi1 + 16*w + 4*lg);
        #pragma unroll
        for (int mt = 0; mt < 4; ++mt) { acc1[mt][0]=bv.x; acc1[mt][1]=bv.y; acc1[mt][2]=bv.z; acc1[mt][3]=bv.w; }
        for (int kt = 0; kt < 4; ++kt) {
            short8 bh, bl;
            load_bfrag<PRE>(WB+OFF_WI1H, WB+OFF_WI1L, Wi1, 128, 8, kt, w, l, bh, bl);
            #pragma unroll
            for (int mt = 0; mt < 4; ++mt) {
                const int o = swzofs(16*mt + lr, 128 + 32*kt + 8*lg);
                acc1[mt] = mfma3(bh, bl, *(const short8*)&hbH[o], *(const short8*)&hbL[o], acc1[mt]);
            }
        }
        #pragma unroll
        for (int mt = 0; mt < 4; ++mt) {
            f32x4 v;
            #pragma unroll
            for (int r = 0; r < 4; ++r) v[r] = fmaxf(acc1[mt][r], 0.f);
            us4 h, lo; split4(v, h, lo);
            const int o = swzofs(16*mt + lr, 16*w + 4*lg);
            *(us4*)&hbH[o] = h; *(us4*)&hbL[o] = lo;
        }
    }
    __syncthreads();

    // ---- stage 2: xf = h1 @ Wi2 + bi2 (kept in regs) -> then cols [128,256) ----
    f32x4 acc2[4];
    {
        const float4 bv = *(const float4*)(bi2 + 16*w + 4*lg);
        #pragma unroll
        for (int mt = 0; mt < 4; ++mt) { acc2[mt][0]=bv.x; acc2[mt][1]=bv.y; acc2[mt][2]=bv.z; acc2[mt][3]=bv.w; }
        for (int kt = 0; kt < 4; ++kt) {
            short8 bh, bl;
            load_bfrag<PRE>(WB+OFF_WI2H, WB+OFF_WI2L, Wi2, 128, 8, kt, w, l, bh, bl);
            #pragma unroll
            for (int mt = 0; mt < 4; ++mt) {
                const int o = swzofs(16*mt + lr, 32*kt + 8*lg);
                acc2[mt] = mfma3(bh, bl, *(const short8*)&hbH[o], *(const short8*)&hbL[o], acc2[mt]);
            }
        }
        // x region is dead (only s1 read it, barrier passed): write xf there.
        #pragma unroll
        for (int mt = 0; mt < 4; ++mt) {
            us4 h, lo; split4(acc2[mt], h, lo);
            const int o = swzofs(16*mt + lr, 128 + 16*w + 4*lg);
            *(us4*)&hbH[o] = h; *(us4*)&hbL[o] = lo;
        }
    }
    __syncthreads();

    // ---- stage 3: xi = relu(xf @ We); a*xi -> cols [0,128) ----
    {
        f32x4 acc3[4];
        #pragma unroll
        for (int mt = 0; mt < 4; ++mt) { acc3[mt][0]=0.f; acc3[mt][1]=0.f; acc3[mt][2]=0.f; acc3[mt][3]=0.f; }
        for (int kt = 0; kt < 4; ++kt) {
            short8 eh, el;
            load_bfrag<PRE>(WB+OFF_WEH, WB+OFF_WEL, We, 128, 8, kt, w, l, eh, el);
            #pragma unroll
            for (int mt = 0; mt < 4; ++mt) {
                const int o = swzofs(16*mt + lr, 128 + 32*kt + 8*lg);
                acc3[mt] = mfma3(eh, el, *(const short8*)&hbH[o], *(const short8*)&hbL[o], acc3[mt]);
            }
        }
        const float4 sv = *(const float4*)(sums + b*128 + 16*w + 4*lg);
        const float rinv[4] = {1.f/sv.x, 1.f/sv.y, 1.f/sv.z, 1.f/sv.w};
        #pragma unroll
        for (int mt = 0; mt < 4; ++mt) {
            f32x4 v;
            #pragma unroll
            for (int r = 0; r < 4; ++r) {
                const float aa = valid[mt] ? __expf(acc2[mt][r]) * rinv[r] : 0.0f;
                v[r] = aa * fmaxf(acc3[mt][r], 0.f);
            }
            us4 h, lo; split4(v, h, lo);
            const int o = swzofs(16*mt + lr, 16*w + 4*lg);
            *(us4*)&hbH[o] = h; *(us4*)&hbL[o] = lo;
        }
    }
    __syncthreads();

    // ---- stage 4: g = relu(h @ Wo1 + bo1), K=256 over h=[a*xi | xf] ----
    f32x4 acc4[4][2];
    #pragma unroll
    for (int n = 0; n < 2; ++n) {
        const float4 bv = *(const float4*)(bo1 + 16*(2*w + n) + 4*lg);
        #pragma unroll
        for (int mt = 0; mt < 4; ++mt) {
            acc4[mt][n][0]=bv.x; acc4[mt][n][1]=bv.y; acc4[mt][n][2]=bv.z; acc4[mt][n][3]=bv.w;
        }
    }
    for (int kt = 0; kt < 8; ++kt) {
        short8 oh[2], ol[2];
        #pragma unroll
        for (int n = 0; n < 2; ++n)
            load_bfrag<PRE>(WB+OFF_WO1H, WB+OFF_WO1L, Wo1, 256, 16, kt, 2*w+n, l, oh[n], ol[n]);
        #pragma unroll
        for (int mt = 0; mt < 4; ++mt) {
            const int o = swzofs(16*mt + lr, 32*kt + 8*lg);
            const short8 ah = *(const short8*)&hbH[o];
            const short8 al = *(const short8*)&hbL[o];
            #pragma unroll
            for (int n = 0; n < 2; ++n) acc4[mt][n] = mfma3(oh[n], ol[n], ah, al, acc4[mt][n]);
        }
    }

    // ---- stage 5: out = relu(g) @ Wo2 + bo2, reduce 256 -> 1 per row ----
    {
        float outp[4] = {0.f, 0.f, 0.f, 0.f};
        #pragma unroll
        for (int n = 0; n < 2; ++n) {
            const float4 wv = *(const float4*)(Wo2 + 16*(2*w + n) + 4*lg);
            #pragma unroll
            for (int mt = 0; mt < 4; ++mt) {
                outp[mt] += fmaxf(acc4[mt][n][0], 0.f)*wv.x + fmaxf(acc4[mt][n][1], 0.f)*wv.y
                          + fmaxf(acc4[mt][n][2], 0.f)*wv.z + fmaxf(acc4[mt][n][3], 0.f)*wv.w;
            }
        }
        #pragma unroll
        for (int mt = 0; mt < 4; ++mt) {
            outp[mt] += __shfl_xor(outp[mt], 16);
            outp[mt] += __shfl_xor(outp[mt], 32);
        }
        if (l < 16) {
            #pragma unroll
            for (int mt = 0; mt < 4; ++mt) red[w][16*mt + lr] = outp[mt];
        }
        __syncthreads();
        if (tid < ROWS) {
            out[(long)b*NCUBE + e0 + tid] =
                red[0][tid] + red[1][tid] + red[2][tid] + red[3][tid] +
                red[4][tid] + red[5][tid] + red[6][tid] + red[7][tid] + bo2[0];
        }
    }
}

extern "C" void kernel_launch(void* const* d_in, const int* in_sizes, int n_in,
                              void* d_out, int out_size, void* d_ws, size_t ws_size,
                              hipStream_t stream) {
    const float*         x    = (const float*)d_in[0];
    const unsigned char* mask = (const unsigned char*)d_in[1];
    const float* Wi1 = (const float*)d_in[2];
    const float* bi1 = (const float*)d_in[3];
    const float* Wi2 = (const float*)d_in[4];
    const float* bi2 = (const float*)d_in[5];
    const float* We  = (const float*)d_in[6];
    const float* Wo1 = (const float*)d_in[7];
    const float* bo1 = (const float*)d_in[8];
    const float* Wo2 = (const float*)d_in[9];
    const float* bo2 = (const float*)d_in[10];
    float* out  = (float*)d_out;
    float* sums = (float*)d_ws;
    int*   cnt   = (int*)((char*)d_ws + 2048);
    int*   vlist = (int*)((char*)d_ws + 4096);

    const bool compact = ws_size >= (size_t)(WBOFF_COMPACT + WB_BYTES);
    const size_t wboff = compact ? WBOFF_COMPACT : WBOFF_SMALL;
    const bool pre     = ws_size >= wboff + WB_BYTES;
    unsigned short* WB = (unsigned short*)((char*)d_ws + wboff);

    hipMemsetAsync(d_ws, 0, 2048 + Bn*sizeof(int), stream);
    if (pre) prep_kernel<<<56, 256, 0, stream>>>(Wi1, Wi2, We, Wo1, WB);

    if (compact) {
        count_valid<<<Bn*250, 256, 0, stream>>>(mask, cnt, vlist);
        sums_kernel<true, true><<<Bn*CBLK, 512, 0, stream>>>(x, mask, Wi1, bi1, Wi2, bi2,
                                                             sums, cnt, vlist, WB);
        full_kernel<true><<<Bn*BPB, 512, 0, stream>>>(x, mask, Wi1, bi1, Wi2, bi2, We,
                                                      Wo1, bo1, Wo2, bo2, sums, WB, out);
    } else if (pre) {
        sums_kernel<true, false><<<Bn*BPB, 512, 0, stream>>>(x, mask, Wi1, bi1, Wi2, bi2,
                                                             sums, cnt, vlist, WB);
        full_kernel<true><<<Bn*BPB, 512, 0, stream>>>(x, mask, Wi1, bi1, Wi2, bi2, We,
                                                      Wo1, bo1, Wo2, bo2, sums, WB, out);
    } else {
        sums_kernel<false, false><<<Bn*BPB, 512, 0, stream>>>(x, mask, Wi1, bi1, Wi2, bi2,
                                                              sums, cnt, vlist, WB);
        full_kernel<false><<<Bn*BPB, 512, 0, stream>>>(x, mask, Wi1, bi1, Wi2, bi2, We,
                                                       Wo1, bo1, Wo2, bo2, sums, WB, out);
    }
}